// Round 1
// baseline (81.698 us; speedup 1.0000x reference)
//
#include <hip/hip_runtime.h>
#include <math.h>

// Problem constants (from reference): B=32, S=8192, D=256, f32 in/out.
constexpr int NB = 32;
constexpr int NS = 8192;
constexpr int ND = 256;
constexpr int BLOCKS_PER_BATCH = 32;
constexpr int ROWS_PER_BLOCK   = NS / BLOCKS_PER_BATCH;  // 256
constexpr int NWAVES = 4;                                // 256 threads / 64
constexpr int PSTRIDE = ND + 2;                          // o[256], m, l

// Kernel 1: one pass over `sequence`. Each wave owns one row at a time:
// lane i loads seq[b,s,4i..4i+3] (float4, coalesced 1KiB/row), dot with
// vector fragment, 6-step butterfly reduce, online-softmax accumulate
// (m, l, o4 per lane). Raw score written to the attn region of d_out
// (used as scratch until kernel 3 normalizes it in place).
__global__ __launch_bounds__(256) void k1_partial(
    const float* __restrict__ seq,
    const float* __restrict__ vec,
    const float* __restrict__ mask,
    float* __restrict__ scores,     // aliases d_out + B*D (attn region)
    float* __restrict__ partials)   // [NB*BLOCKS_PER_BATCH][PSTRIDE]
{
    const int blk   = blockIdx.x;
    const int b     = blk / BLOCKS_PER_BATCH;
    const int chunk = blk % BLOCKS_PER_BATCH;
    const int tid   = threadIdx.x;
    const int lane  = tid & 63;
    const int wave  = tid >> 6;

    const float4 v = *reinterpret_cast<const float4*>(vec + b * ND + lane * 4);

    float  m = -1e30f;   // finite sentinel: avoids inf arithmetic in fast exp
    float  l = 0.f;
    float4 o = make_float4(0.f, 0.f, 0.f, 0.f);

    const int row0 = chunk * ROWS_PER_BLOCK;
    const float* __restrict__ seqb   = seq  + (size_t)b * NS * ND;
    const float* __restrict__ maskb  = mask + (size_t)b * NS;
    float* __restrict__       scoreb = scores + (size_t)b * NS;

    for (int r = wave; r < ROWS_PER_BLOCK; r += NWAVES) {
        const int s = row0 + r;
        const float4 x = *reinterpret_cast<const float4*>(seqb + (size_t)s * ND + lane * 4);
        float dot = x.x * v.x + x.y * v.y + x.z * v.z + x.w * v.w;
        #pragma unroll
        for (int off = 32; off > 0; off >>= 1)
            dot += __shfl_xor(dot, off, 64);
        if (lane == 0) scoreb[s] = dot;
        const float msk = maskb[s];                 // wave-uniform broadcast load
        const float mn    = fmaxf(m, dot);          // NOTE: max is UNMASKED (per ref)
        const float scale = __expf(m - mn);
        const float e     = __expf(dot - mn) * msk;
        l   = l   * scale + e;
        o.x = o.x * scale + e * x.x;
        o.y = o.y * scale + e * x.y;
        o.z = o.z * scale + e * x.z;
        o.w = o.w * scale + e * x.w;
        m = mn;
    }

    // combine the 4 waves' partials within the block
    __shared__ float so[NWAVES][ND];   // 4 KiB
    __shared__ float sml[NWAVES][2];
    *reinterpret_cast<float4*>(&so[wave][lane * 4]) = o;
    if (lane == 0) { sml[wave][0] = m; sml[wave][1] = l; }
    __syncthreads();

    const float M = fmaxf(fmaxf(sml[0][0], sml[1][0]), fmaxf(sml[2][0], sml[3][0]));
    float L = 0.f, O = 0.f;
    #pragma unroll
    for (int w = 0; w < NWAVES; ++w) {
        const float wgt = __expf(sml[w][0] - M);
        L += sml[w][1] * wgt;
        O += so[w][tid] * wgt;
    }
    float* p = partials + (size_t)blk * PSTRIDE;
    p[tid] = O;
    if (tid == 0) { p[ND] = M; p[ND + 1] = L; }
}

// Kernel 2: per-batch cross-block reduction (32 partials), writes pooled
// and the per-batch (M, L) for the attn normalization pass.
__global__ __launch_bounds__(256) void k2_reduce(
    const float* __restrict__ partials,
    float* __restrict__ pooled,     // d_out [NB][ND]
    float* __restrict__ finals)     // [NB][2] = (M, L)
{
    const int b   = blockIdx.x;
    const int tid = threadIdx.x;
    __shared__ float w[BLOCKS_PER_BATCH];
    __shared__ float sM, sL;
    const float* __restrict__ pb = partials + (size_t)b * BLOCKS_PER_BATCH * PSTRIDE;

    if (tid < BLOCKS_PER_BATCH) {
        const float mi = pb[tid * PSTRIDE + ND];
        float M = mi;
        #pragma unroll
        for (int off = 16; off > 0; off >>= 1)
            M = fmaxf(M, __shfl_xor(M, off, 32));
        const float li = pb[tid * PSTRIDE + ND + 1];
        const float wi = __expf(mi - M);
        w[tid] = wi;
        float L = li * wi;
        #pragma unroll
        for (int off = 16; off > 0; off >>= 1)
            L += __shfl_xor(L, off, 32);
        if (tid == 0) { sM = M; sL = L; }
    }
    __syncthreads();

    float acc = 0.f;
    #pragma unroll 4
    for (int i = 0; i < BLOCKS_PER_BATCH; ++i)
        acc += pb[i * PSTRIDE + tid] * w[i];
    pooled[b * ND + tid] = acc / (sL + 1e-13f);
    if (tid == 0) { finals[b * 2] = sM; finals[b * 2 + 1] = sL; }
}

// Kernel 3: normalize raw scores (in d_out's attn region) in place:
// attn = exp(score - M) * mask / (L + 1e-13). float4-vectorized, 2 MiB total.
__global__ __launch_bounds__(256) void k3_norm(
    float* __restrict__ attn,
    const float* __restrict__ mask,
    const float* __restrict__ finals)
{
    const int idx = blockIdx.x * 256 + threadIdx.x;
    const int i4  = idx * 4;                  // NS % 4 == 0 -> same batch
    const int b   = i4 / NS;
    const float M  = finals[b * 2];
    const float rL = 1.0f / (finals[b * 2 + 1] + 1e-13f);
    float4 sc = *reinterpret_cast<float4*>(attn + i4);
    const float4 mk = *reinterpret_cast<const float4*>(mask + i4);
    sc.x = __expf(sc.x - M) * mk.x * rL;
    sc.y = __expf(sc.y - M) * mk.y * rL;
    sc.z = __expf(sc.z - M) * mk.z * rL;
    sc.w = __expf(sc.w - M) * mk.w * rL;
    *reinterpret_cast<float4*>(attn + i4) = sc;
}

extern "C" void kernel_launch(void* const* d_in, const int* in_sizes, int n_in,
                              void* d_out, int out_size, void* d_ws, size_t ws_size,
                              hipStream_t stream)
{
    const float* seq  = (const float*)d_in[0];   // [B, S, D]
    const float* vec  = (const float*)d_in[1];   // [B, D]
    const float* mask = (const float*)d_in[2];   // [B, S]

    float* pooled = (float*)d_out;               // [B, D]
    float* attn   = pooled + NB * ND;            // [B, S] (scores scratch first)

    float* partials = (float*)d_ws;                                  // ~1.03 MiB
    float* finals   = partials + (size_t)NB * BLOCKS_PER_BATCH * PSTRIDE;

    k1_partial<<<NB * BLOCKS_PER_BATCH, 256, 0, stream>>>(seq, vec, mask, attn, partials);
    k2_reduce<<<NB, 256, 0, stream>>>(partials, pooled, finals);
    k3_norm<<<NB * NS / (256 * 4), 256, 0, stream>>>(attn, mask, finals);
}

// Round 2
// 53.354 us; speedup vs baseline: 1.5312x; 1.5312x over previous
//
#include <hip/hip_runtime.h>
#include <math.h>

// Problem constants (from reference): B=32, S=8192, D=256, f32 in/out.
constexpr int NB  = 32;
constexpr int NS  = 8192;
constexpr int ND  = 256;
constexpr int BPB = 64;                 // blocks per batch (ws is ~1 GiB; 2048*258*4B = 2.1 MiB used)
constexpr int RPB = NS / BPB;           // 128 rows per block
constexpr int NWAVES = 4;               // 256 threads
constexpr int RBATCH = 8;               // rows per wave-iteration (ILP batch)
constexpr int PSTRIDE = ND + 2;         // o[256], m, l

// Kernel 1: single pass over `sequence` (the 256 MiB stream).
// Each wave processes 8 rows per iteration: 8 independent float4 loads in
// flight, shuffle-reduce 8 dots concurrently (latency pipelined), ONE
// online-softmax rescale per 8-row group (exact), then 8 accumulates.
// Raw scores parked in d_out's attn region (normalized in place by k2).
__global__ __launch_bounds__(256) void k1_partial(
    const float* __restrict__ seq,
    const float* __restrict__ vec,
    const float* __restrict__ mask,
    float* __restrict__ scores,     // d_out + NB*ND (attn region, raw scores for now)
    float* __restrict__ partials)   // [NB*BPB][PSTRIDE]
{
    const int blk   = blockIdx.x;
    const int b     = blk / BPB;
    const int chunk = blk % BPB;
    const int tid   = threadIdx.x;
    const int lane  = tid & 63;
    const int wave  = tid >> 6;

    const float4 v = *reinterpret_cast<const float4*>(vec + b * ND + lane * 4);

    float  m = -1e30f;   // finite sentinel
    float  l = 0.f;
    float4 o = make_float4(0.f, 0.f, 0.f, 0.f);

    const int row0 = chunk * RPB;
    const float* __restrict__ seqb   = seq  + (size_t)b * NS * ND;
    const float* __restrict__ maskb  = mask + (size_t)b * NS;
    float* __restrict__       scoreb = scores + (size_t)b * NS;

    for (int r0 = wave * RBATCH; r0 < RPB; r0 += NWAVES * RBATCH) {
        const int s0 = row0 + r0;
        float4 x[RBATCH];
        float  dot[RBATCH];
        #pragma unroll
        for (int k = 0; k < RBATCH; ++k)
            x[k] = *reinterpret_cast<const float4*>(seqb + (size_t)(s0 + k) * ND + lane * 4);
        #pragma unroll
        for (int k = 0; k < RBATCH; ++k)
            dot[k] = x[k].x * v.x + x[k].y * v.y + x[k].z * v.z + x[k].w * v.w;
        // 6-step butterfly over 8 independent values: DS latency pipelined
        #pragma unroll
        for (int off = 32; off > 0; off >>= 1) {
            #pragma unroll
            for (int k = 0; k < RBATCH; ++k)
                dot[k] += __shfl_xor(dot[k], off, 64);
        }
        if (lane == 0) {
            *reinterpret_cast<float4*>(scoreb + s0)     = make_float4(dot[0], dot[1], dot[2], dot[3]);
            *reinterpret_cast<float4*>(scoreb + s0 + 4) = make_float4(dot[4], dot[5], dot[6], dot[7]);
        }
        const float4 mk0 = *reinterpret_cast<const float4*>(maskb + s0);
        const float4 mk1 = *reinterpret_cast<const float4*>(maskb + s0 + 4);

        const float mx = fmaxf(fmaxf(fmaxf(dot[0], dot[1]), fmaxf(dot[2], dot[3])),
                               fmaxf(fmaxf(dot[4], dot[5]), fmaxf(dot[6], dot[7])));
        const float mn    = fmaxf(m, mx);      // max is UNMASKED (per reference)
        const float scale = __expf(m - mn);

        float e[RBATCH];
        e[0] = __expf(dot[0] - mn) * mk0.x;
        e[1] = __expf(dot[1] - mn) * mk0.y;
        e[2] = __expf(dot[2] - mn) * mk0.z;
        e[3] = __expf(dot[3] - mn) * mk0.w;
        e[4] = __expf(dot[4] - mn) * mk1.x;
        e[5] = __expf(dot[5] - mn) * mk1.y;
        e[6] = __expf(dot[6] - mn) * mk1.z;
        e[7] = __expf(dot[7] - mn) * mk1.w;

        l   *= scale;
        o.x *= scale; o.y *= scale; o.z *= scale; o.w *= scale;
        #pragma unroll
        for (int k = 0; k < RBATCH; ++k) {
            l   += e[k];
            o.x += e[k] * x[k].x;
            o.y += e[k] * x[k].y;
            o.z += e[k] * x[k].z;
            o.w += e[k] * x[k].w;
        }
        m = mn;
    }

    // combine the 4 waves' partials within the block
    __shared__ float so[NWAVES][ND];   // 4 KiB
    __shared__ float sml[NWAVES][2];
    *reinterpret_cast<float4*>(&so[wave][lane * 4]) = o;
    if (lane == 0) { sml[wave][0] = m; sml[wave][1] = l; }
    __syncthreads();

    const float M = fmaxf(fmaxf(sml[0][0], sml[1][0]), fmaxf(sml[2][0], sml[3][0]));
    float L = 0.f, O = 0.f;
    #pragma unroll
    for (int w = 0; w < NWAVES; ++w) {
        const float wgt = __expf(sml[w][0] - M);
        L += sml[w][1] * wgt;
        O += so[w][tid] * wgt;
    }
    float* p = partials + (size_t)blk * PSTRIDE;
    p[tid] = O;
    if (tid == 0) { p[ND] = M; p[ND + 1] = L; }
}

// Kernel 2: per-batch cross-block reduction (64 partials) -> pooled, then
// normalize the raw scores in d_out's attn region in place (k3 merged in).
__global__ __launch_bounds__(256) void k2_reduce(
    const float* __restrict__ partials,
    const float* __restrict__ mask,
    float* __restrict__ pooled,     // d_out [NB][ND]
    float* __restrict__ attn)       // d_out + NB*ND [NB][NS]
{
    const int b   = blockIdx.x;
    const int tid = threadIdx.x;
    __shared__ float w[BPB];
    __shared__ float sM, sL;
    const float* __restrict__ pb = partials + (size_t)b * BPB * PSTRIDE;

    if (tid < BPB) {   // wave 0 exactly
        const float mi = pb[tid * PSTRIDE + ND];
        float M = mi;
        #pragma unroll
        for (int off = 32; off > 0; off >>= 1)
            M = fmaxf(M, __shfl_xor(M, off, 64));
        const float li = pb[tid * PSTRIDE + ND + 1];
        const float wi = __expf(mi - M);
        w[tid] = wi;
        float L = li * wi;
        #pragma unroll
        for (int off = 32; off > 0; off >>= 1)
            L += __shfl_xor(L, off, 64);
        if (tid == 0) { sM = M; sL = L; }
    }
    __syncthreads();

    float acc = 0.f;
    #pragma unroll 8
    for (int i = 0; i < BPB; ++i)
        acc += pb[i * PSTRIDE + tid] * w[i];
    const float rL = 1.0f / (sL + 1e-13f);
    pooled[b * ND + tid] = acc * rL;

    // normalize scores -> attn in place (3 MiB total across 32 blocks)
    const float M = sM;
    float4* __restrict__ ab = reinterpret_cast<float4*>(attn + (size_t)b * NS);
    const float4* __restrict__ mb = reinterpret_cast<const float4*>(mask + (size_t)b * NS);
    for (int i = tid; i < NS / 4; i += 256) {
        float4 sc = ab[i];
        const float4 mk = mb[i];
        sc.x = __expf(sc.x - M) * mk.x * rL;
        sc.y = __expf(sc.y - M) * mk.y * rL;
        sc.z = __expf(sc.z - M) * mk.z * rL;
        sc.w = __expf(sc.w - M) * mk.w * rL;
        ab[i] = sc;
    }
}

extern "C" void kernel_launch(void* const* d_in, const int* in_sizes, int n_in,
                              void* d_out, int out_size, void* d_ws, size_t ws_size,
                              hipStream_t stream)
{
    const float* seq  = (const float*)d_in[0];   // [B, S, D]
    const float* vec  = (const float*)d_in[1];   // [B, D]
    const float* mask = (const float*)d_in[2];   // [B, S]

    float* pooled = (float*)d_out;               // [B, D]
    float* attn   = pooled + NB * ND;            // [B, S]

    float* partials = (float*)d_ws;              // 2048 * 258 * 4 B ~= 2.1 MiB

    k1_partial<<<NB * BPB, 256, 0, stream>>>(seq, vec, mask, attn, partials);
    k2_reduce<<<NB, 256, 0, stream>>>(partials, mask, pooled, attn);
}

// Round 3
// 51.783 us; speedup vs baseline: 1.5777x; 1.0303x over previous
//
#include <hip/hip_runtime.h>
#include <math.h>

// Problem constants: B=32, S=8192, D=256, f32 in/out.
constexpr int NB  = 32;
constexpr int NS  = 8192;
constexpr int ND  = 256;
constexpr int BPB = 64;                  // blocks per batch
constexpr int RPB = NS / BPB;            // 128 rows per block
constexpr int NWAVES = 4;                // 256 threads
constexpr int RBATCH = 8;                // rows per wave-iteration (4 per half-wave)
constexpr int NITER  = RPB / (NWAVES * RBATCH);  // 4
constexpr int PSTRIDE = ND + 2;          // o[256], m, l
constexpr int NPART = NWAVES * 2;        // 8 half-wave partials per block

// Kernel 1: one pass over `sequence`. Half-wave decomposition: 32 lanes own
// one row (8 floats/lane -> 2x float4 loads), so the dot-reduce is a 5-step
// butterfly within the 32-lane half and each lane does 4 exps per 8-row
// group. Next group's 8 loads are prefetched into a second register set
// (statically unrolled double-buffer). Each half-wave keeps independent
// online-softmax state (m, l, o[8 dims/lane]); 8 half-wave partials combine
// in LDS at block end.
__global__ __launch_bounds__(256) void k1_partial(
    const float* __restrict__ seq,
    const float* __restrict__ vec,
    const float* __restrict__ mask,
    float* __restrict__ scores,     // d_out + NB*ND (attn region, raw scores)
    float* __restrict__ partials)   // [NB*BPB][PSTRIDE]
{
    const int blk   = blockIdx.x;
    const int b     = blk / BPB;
    const int chunk = blk % BPB;
    const int tid   = threadIdx.x;
    const int lane  = tid & 63;
    const int wave  = tid >> 6;
    const int h     = lane >> 5;    // half-wave id
    const int sl    = lane & 31;    // sublane within half

    const float* vb = vec + b * ND + sl * 8;
    const float4 v0 = *reinterpret_cast<const float4*>(vb);
    const float4 v1 = *reinterpret_cast<const float4*>(vb + 4);

    float  m = -1e30f;   // finite sentinel (unmasked max, per reference)
    float  l = 0.f;
    float4 o0 = make_float4(0.f, 0.f, 0.f, 0.f);
    float4 o1 = make_float4(0.f, 0.f, 0.f, 0.f);

    const int row0 = chunk * RPB;
    const float* __restrict__ seqb   = seq  + (size_t)b * NS * ND;
    const float* __restrict__ maskb  = mask + (size_t)b * NS;
    float* __restrict__       scoreb = scores + (size_t)b * NS;

    // this (wave, half)'s first row; iter stride = NWAVES*RBATCH = 32 rows
    const int   sbase = row0 + wave * RBATCH + h * 4;
    const float* base = seqb + (size_t)sbase * ND + sl * 8;

    float4 xa0[4], xa1[4], xb0[4], xb1[4];   // double-buffered: 4 rows x 8 floats

    auto LOAD = [&](float4 (&x0)[4], float4 (&x1)[4], int it) {
        const float* p = base + (size_t)it * (NWAVES * RBATCH) * ND;
        #pragma unroll
        for (int k = 0; k < 4; ++k) {
            x0[k] = *reinterpret_cast<const float4*>(p + (size_t)k * ND);
            x1[k] = *reinterpret_cast<const float4*>(p + (size_t)k * ND + 4);
        }
    };

    auto PROC = [&](const float4 (&x0)[4], const float4 (&x1)[4], int it) {
        float dot[4];
        #pragma unroll
        for (int k = 0; k < 4; ++k)
            dot[k] = x0[k].x * v0.x + x0[k].y * v0.y + x0[k].z * v0.z + x0[k].w * v0.w
                   + x1[k].x * v1.x + x1[k].y * v1.y + x1[k].z * v1.z + x1[k].w * v1.w;
        // 5-step butterfly within the 32-lane half (4 independent chains)
        #pragma unroll
        for (int off = 1; off < 32; off <<= 1) {
            #pragma unroll
            for (int k = 0; k < 4; ++k)
                dot[k] += __shfl_xor(dot[k], off, 64);
        }
        const int s0h = sbase + it * (NWAVES * RBATCH);
        if (sl == 0)
            *reinterpret_cast<float4*>(scoreb + s0h) =
                make_float4(dot[0], dot[1], dot[2], dot[3]);
        const float4 mk = *reinterpret_cast<const float4*>(maskb + s0h);

        const float mx = fmaxf(fmaxf(dot[0], dot[1]), fmaxf(dot[2], dot[3]));
        const float mn = fmaxf(m, mx);
        const float scale = __expf(m - mn);
        float e[4];
        e[0] = __expf(dot[0] - mn) * mk.x;
        e[1] = __expf(dot[1] - mn) * mk.y;
        e[2] = __expf(dot[2] - mn) * mk.z;
        e[3] = __expf(dot[3] - mn) * mk.w;
        l    = l    * scale + e[0] + e[1] + e[2] + e[3];
        o0.x = o0.x * scale; o0.y = o0.y * scale; o0.z = o0.z * scale; o0.w = o0.w * scale;
        o1.x = o1.x * scale; o1.y = o1.y * scale; o1.z = o1.z * scale; o1.w = o1.w * scale;
        #pragma unroll
        for (int k = 0; k < 4; ++k) {
            o0.x += e[k] * x0[k].x; o0.y += e[k] * x0[k].y;
            o0.z += e[k] * x0[k].z; o0.w += e[k] * x0[k].w;
            o1.x += e[k] * x1[k].x; o1.y += e[k] * x1[k].y;
            o1.z += e[k] * x1[k].z; o1.w += e[k] * x1[k].w;
        }
        m = mn;
    };

    LOAD(xa0, xa1, 0);
    #pragma unroll
    for (int it = 0; it < NITER; ++it) {
        if ((it & 1) == 0) {
            if (it + 1 < NITER) LOAD(xb0, xb1, it + 1);
            PROC(xa0, xa1, it);
        } else {
            if (it + 1 < NITER) LOAD(xa0, xa1, it + 1);
            PROC(xb0, xb1, it);
        }
    }

    // combine the 8 half-wave partials within the block
    __shared__ float so[NPART][ND];   // 8 KiB
    __shared__ float sml[NPART][2];
    const int u = wave * 2 + h;
    *reinterpret_cast<float4*>(&so[u][sl * 8])     = o0;
    *reinterpret_cast<float4*>(&so[u][sl * 8 + 4]) = o1;
    if (sl == 0) { sml[u][0] = m; sml[u][1] = l; }
    __syncthreads();

    float M = sml[0][0];
    #pragma unroll
    for (int i = 1; i < NPART; ++i) M = fmaxf(M, sml[i][0]);
    float L = 0.f, O = 0.f;
    #pragma unroll
    for (int i = 0; i < NPART; ++i) {
        const float wgt = __expf(sml[i][0] - M);
        L += sml[i][1] * wgt;
        O += so[i][tid] * wgt;
    }
    float* p = partials + (size_t)blk * PSTRIDE;
    p[tid] = O;
    if (tid == 0) { p[ND] = M; p[ND + 1] = L; }
}

// Kernel 2: per-batch cross-block reduction (64 partials) -> pooled + finals.
__global__ __launch_bounds__(256) void k2_reduce(
    const float* __restrict__ partials,
    float* __restrict__ pooled,     // d_out [NB][ND]
    float* __restrict__ finals)     // [NB][2] = (M, L)
{
    const int b   = blockIdx.x;
    const int tid = threadIdx.x;
    __shared__ float w[BPB];
    __shared__ float sM, sL;
    const float* __restrict__ pb = partials + (size_t)b * BPB * PSTRIDE;

    if (tid < BPB) {   // wave 0 exactly (BPB == 64)
        const float mi = pb[tid * PSTRIDE + ND];
        float M = mi;
        #pragma unroll
        for (int off = 32; off > 0; off >>= 1)
            M = fmaxf(M, __shfl_xor(M, off, 64));
        const float li = pb[tid * PSTRIDE + ND + 1];
        const float wi = __expf(mi - M);
        w[tid] = wi;
        float L = li * wi;
        #pragma unroll
        for (int off = 32; off > 0; off >>= 1)
            L += __shfl_xor(L, off, 64);
        if (tid == 0) { sM = M; sL = L; }
    }
    __syncthreads();

    float acc = 0.f;
    #pragma unroll 8
    for (int i = 0; i < BPB; ++i)
        acc += pb[i * PSTRIDE + tid] * w[i];
    const float rL = 1.0f / (sL + 1e-13f);
    pooled[b * ND + tid] = acc * rL;
    if (tid == 0) { finals[b * 2] = sM; finals[b * 2 + 1] = sL; }
}

// Kernel 3: normalize raw scores in place -> attn. 256 blocks, float4/thread.
__global__ __launch_bounds__(256) void k3_norm(
    float* __restrict__ attn,
    const float* __restrict__ mask,
    const float* __restrict__ finals)
{
    const int idx = blockIdx.x * 256 + threadIdx.x;
    const int i4  = idx * 4;                  // NS % 4 == 0 -> same batch
    const int b   = i4 >> 13;                 // / NS
    const float M  = finals[b * 2];
    const float rL = 1.0f / (finals[b * 2 + 1] + 1e-13f);
    float4 sc = *reinterpret_cast<float4*>(attn + i4);
    const float4 mk = *reinterpret_cast<const float4*>(mask + i4);
    sc.x = __expf(sc.x - M) * mk.x * rL;
    sc.y = __expf(sc.y - M) * mk.y * rL;
    sc.z = __expf(sc.z - M) * mk.z * rL;
    sc.w = __expf(sc.w - M) * mk.w * rL;
    *reinterpret_cast<float4*>(attn + i4) = sc;
}

extern "C" void kernel_launch(void* const* d_in, const int* in_sizes, int n_in,
                              void* d_out, int out_size, void* d_ws, size_t ws_size,
                              hipStream_t stream)
{
    const float* seq  = (const float*)d_in[0];   // [B, S, D]
    const float* vec  = (const float*)d_in[1];   // [B, D]
    const float* mask = (const float*)d_in[2];   // [B, S]

    float* pooled = (float*)d_out;               // [B, D]
    float* attn   = pooled + NB * ND;            // [B, S]

    float* partials = (float*)d_ws;                                  // ~2.1 MiB
    float* finals   = partials + (size_t)NB * BPB * PSTRIDE;

    k1_partial<<<NB * BPB, 256, 0, stream>>>(seq, vec, mask, attn, partials);
    k2_reduce<<<NB, 256, 0, stream>>>(partials, pooled, finals);
    k3_norm<<<NB * NS / (256 * 4), 256, 0, stream>>>(attn, mask, finals);
}